// Round 8
// baseline (179.989 us; speedup 1.0000x reference)
//
#include <hip/hip_runtime.h>

#define IN_F 128
#define C1 64
#define NG 128
#define CAT 192
#define DCAP 10240   // per-digit edge capacity (mean 8163, sigma ~90)

typedef unsigned short u16;
typedef unsigned int u32;
typedef __attribute__((ext_vector_type(8))) short bf16x8;
typedef __attribute__((ext_vector_type(4))) float f32x4;

__device__ inline u16 f2bf(float f) {
  u32 u = __float_as_uint(f);
  u = (u + 0x7FFFu + ((u >> 16) & 1u)) >> 16;   // RTNE
  return (u16)u;
}
__device__ inline float bf2f(u16 h) { return __uint_as_float(((u32)h) << 16); }
__device__ inline float bflo(u32 p) { return __uint_as_float(p << 16); }
__device__ inline float bfhi(u32 p) { return __uint_as_float(p & 0xFFFF0000u); }

// ================= zero scratch =================

__global__ void zero_k(int* __restrict__ g, int n) {
  int i = blockIdx.x * 256 + threadIdx.x;
  if (i < n) g[i] = 0;
}

// ================= CSR build (bucketed, u32-packed stage) =================
// digit = dst >> 9; stage entry = src | (localdst << 17)

__global__ __launch_bounds__(256) void stage_k(const int* __restrict__ src,
                                               const int* __restrict__ dst, int e,
                                               int* __restrict__ gcur,
                                               u32* __restrict__ stage, int ndig) {
  __shared__ int h[256];
  __shared__ int cur[256];
  int t = threadIdx.x;
  h[t] = 0;
  __syncthreads();
  int base = blockIdx.x * 4096;
  int mys[16], myd[16];
  #pragma unroll
  for (int i = 0; i < 16; i++) {
    int j = base + t + i * 256;
    if (j < e) {
      mys[i] = src[j];
      myd[i] = dst[j];
      atomicAdd(&h[myd[i] >> 9], 1);
    } else {
      myd[i] = -1;
    }
  }
  __syncthreads();
  int cnt = h[t];
  __syncthreads();
  int gbase = 0;
  if (t < ndig && cnt > 0) gbase = atomicAdd(&gcur[t], cnt);
  h[t] = gbase;
  cur[t] = 0;
  __syncthreads();
  #pragma unroll
  for (int i = 0; i < 16; i++) {
    if (myd[i] >= 0) {
      int d = myd[i] >> 9;
      int r = atomicAdd(&cur[d], 1);
      stage[(size_t)d * DCAP + h[d] + r] = (u32)mys[i] | ((u32)(myd[i] & 511) << 17);
    }
  }
}

__global__ __launch_bounds__(256) void csr_k(const u32* __restrict__ stage,
                                             const int* __restrict__ gcur,
                                             int* __restrict__ rowptr,
                                             int* __restrict__ counts,
                                             float* __restrict__ dinv,
                                             int* __restrict__ csr, int n) {
  __shared__ int hc[512];
  __shared__ int hb[512];
  __shared__ int cu[512];
  __shared__ int sc[256];
  int dg = blockIdx.x;
  int t = threadIdx.x;
  int n0 = dg * 512;
  int nloc = min(n - n0, 512);
  int e0 = dg * DCAP;
  int e1 = e0 + gcur[dg];
  hc[t] = 0; hc[t + 256] = 0;
  __syncthreads();
  for (int j = e0 + t; j < e1; j += 256) atomicAdd(&hc[stage[j] >> 17], 1);
  __syncthreads();
  int a0 = hc[2 * t], a1 = hc[2 * t + 1];
  int s = a0 + a1;
  sc[t] = s;
  __syncthreads();
  #pragma unroll
  for (int off = 1; off < 256; off <<= 1) {
    int x = sc[t] + ((t >= off) ? sc[t - off] : 0);
    __syncthreads();
    sc[t] = x;
    __syncthreads();
  }
  int excl = sc[t] - s;
  hb[2 * t] = excl;
  hb[2 * t + 1] = excl + a0;
  cu[2 * t] = 0; cu[2 * t + 1] = 0;
  __syncthreads();
  for (int i = t; i < nloc; i += 256) {
    int node = n0 + i;
    rowptr[node] = e0 + hb[i];
    counts[node] = hc[i];
    dinv[node] = rsqrtf((float)hc[i] + 1.0f);  // +1 self loop
  }
  __syncthreads();
  for (int j = e0 + t; j < e1; j += 256) {
    u32 p = stage[j];
    int li = p >> 17;
    int r = atomicAdd(&cu[li], 1);
    csr[e0 + hb[li] + r] = (int)(p & 0x1FFFFu);
  }
}

// ================= MFMA GEMM  Y[N,64](bf16) = X[N,K] @ W[K,64] =================

template <int K, bool IN_BF16>
__global__ __launch_bounds__(256) void gemm_mfma_k(const void* __restrict__ Xv,
                                                   const float* __restrict__ W,
                                                   u16* __restrict__ Y, int n) {
  constexpr int KK = K / 32;
  constexpr int XSN = 2048 * KK;
  constexpr int TOT = 4096 * KK;
  constexpr int SMEMN = (TOT > 9216) ? TOT : 9216;
  __shared__ u16 smem[SMEMN];
  u16* Xs = smem;
  u16* Ws = smem + XSN;
  int t = threadIdx.x;
  int row0 = blockIdx.x * 64;

  for (int idx = t; idx < K * 16; idx += 256) {
    int k = idx >> 4, c4 = (idx & 15) * 4;
    float4 wv = *(const float4*)(W + (size_t)k * 64 + c4);
    int kk = k >> 5, k8 = (k & 31) >> 3, kr = k & 7;
    float wa[4] = {wv.x, wv.y, wv.z, wv.w};
    #pragma unroll
    for (int j = 0; j < 4; j++) {
      int c = c4 + j;
      u32 byte = (u32)(((kk * 64 + c) * 32 + k8 * 8 + kr) * 2);
      byte ^= (u32)((c & 7) << 4);
      *(u16*)((char*)Ws + byte) = f2bf(wa[j]);
    }
  }

  for (int idx = t; idx < 8 * K; idx += 256) {
    int r = idx / (K / 8);
    int c8 = idx % (K / 8);
    int gr = row0 + r;
    u16 vals[8];
    if (gr < n) {
      if (IN_BF16) {
        *(uint4*)vals = *(const uint4*)((const u16*)Xv + (size_t)gr * K + c8 * 8);
      } else {
        const float4 x0 = *(const float4*)((const float*)Xv + (size_t)gr * K + c8 * 8);
        const float4 x1 = *(const float4*)((const float*)Xv + (size_t)gr * K + c8 * 8 + 4);
        vals[0] = f2bf(x0.x); vals[1] = f2bf(x0.y); vals[2] = f2bf(x0.z); vals[3] = f2bf(x0.w);
        vals[4] = f2bf(x1.x); vals[5] = f2bf(x1.y); vals[6] = f2bf(x1.z); vals[7] = f2bf(x1.w);
      }
    } else {
      #pragma unroll
      for (int j = 0; j < 8; j++) vals[j] = 0;
    }
    int wrow = r >> 4, row = r & 15, kk = c8 >> 2, k8 = c8 & 3;
    u32 byte = (u32)((((wrow * KK + kk) * 16 + row) * 32 + k8 * 8) * 2);
    byte ^= (u32)((row & 7) << 4);
    *(uint4*)((char*)Xs + byte) = *(uint4*)vals;
  }
  __syncthreads();

  int w = t >> 6, l = t & 63;
  int lrow = l & 15, lk = l >> 4;
  bf16x8 bfrag[KK][4];
  #pragma unroll
  for (int kk = 0; kk < KK; kk++) {
    #pragma unroll
    for (int cb = 0; cb < 4; cb++) {
      int col = cb * 16 + lrow;
      u32 byte = (u32)(((kk * 64 + col) * 32 + lk * 8) * 2);
      byte ^= (u32)((col & 7) << 4);
      bfrag[kk][cb] = *(bf16x8*)((char*)Ws + byte);
    }
  }
  f32x4 acc[4] = {};
  #pragma unroll
  for (int kk = 0; kk < KK; kk++) {
    u32 abyte = (u32)((((w * KK + kk) * 16 + lrow) * 32 + lk * 8) * 2);
    abyte ^= (u32)((lrow & 7) << 4);
    bf16x8 a = *(bf16x8*)((char*)Xs + abyte);
    #pragma unroll
    for (int cb = 0; cb < 4; cb++) {
      acc[cb] = __builtin_amdgcn_mfma_f32_16x16x32_bf16(a, bfrag[kk][cb], acc[cb], 0, 0, 0);
    }
  }
  __syncthreads();

  #pragma unroll
  for (int cb = 0; cb < 4; cb++) {
    #pragma unroll
    for (int reg = 0; reg < 4; reg++) {
      int r = w * 16 + lk * 4 + reg;
      int c = cb * 16 + lrow;
      smem[r * 72 + c] = f2bf(acc[cb][reg]);
    }
  }
  __syncthreads();
  #pragma unroll
  for (int p = 0; p < 2; p++) {
    int idx = t + p * 256;
    int rr = idx >> 3, ch = idx & 7;
    int gr = row0 + rr;
    if (gr < n) {
      uint4 v = *(uint4*)&smem[rr * 72 + ch * 8];
      *(uint4*)(Y + (size_t)gr * 64 + ch * 8) = v;
    }
  }
}

// ================= gather core (shared by gather_k and gpool_k) =================
// 8 lanes/node; returns post-bias-relu f32 acc[8].

__device__ __forceinline__ void gather_node(const u16* __restrict__ xw,
                                            const int* __restrict__ rowptr,
                                            const int* __restrict__ counts,
                                            const int* __restrict__ csr,
                                            const float* __restrict__ dinv,
                                            const float* __restrict__ bias,
                                            int nid, int lane, float acc[8]) {
  float di = dinv[nid];
  float sc = di * di;
  {
    uint4 a = *(const uint4*)(xw + (size_t)nid * 64 + lane * 8);
    acc[0] = bflo(a.x) * sc; acc[1] = bfhi(a.x) * sc;
    acc[2] = bflo(a.y) * sc; acc[3] = bfhi(a.y) * sc;
    acc[4] = bflo(a.z) * sc; acc[5] = bfhi(a.z) * sc;
    acc[6] = bflo(a.w) * sc; acc[7] = bfhi(a.w) * sc;
  }
  int st = rowptr[nid];
  int cn = counts[nid];
  int myidx = 0;
  float dv = 0.f;
  if (lane < cn) {
    myidx = csr[st + lane];
    dv = dinv[myidx];
  }
  for (int c = 0; c < cn; c += 8) {
    int rem = cn - c;
    uint4 vv[8];
    #pragma unroll
    for (int i = 0; i < 8; i++) {
      int s = __shfl(myidx, i, 8);
      if (i < rem) {
        vv[i] = *(const uint4*)(xw + (size_t)s * 64 + lane * 8);
      } else {
        vv[i] = make_uint4(0, 0, 0, 0);
      }
    }
    float ww[8];
    float myw = dv * di;
    #pragma unroll
    for (int i = 0; i < 8; i++) ww[i] = (i < rem) ? __shfl(myw, i, 8) : 0.f;
    int nxt = 0;
    float ndv = 0.f;
    if (c + 8 < cn && lane < rem - 8) {
      nxt = csr[st + c + 8 + lane];
      ndv = dinv[nxt];
    }
    #pragma unroll
    for (int i = 0; i < 8; i++) {
      float wgt = ww[i];
      acc[0] += bflo(vv[i].x) * wgt; acc[1] += bfhi(vv[i].x) * wgt;
      acc[2] += bflo(vv[i].y) * wgt; acc[3] += bfhi(vv[i].y) * wgt;
      acc[4] += bflo(vv[i].z) * wgt; acc[5] += bfhi(vv[i].z) * wgt;
      acc[6] += bflo(vv[i].w) * wgt; acc[7] += bfhi(vv[i].w) * wgt;
    }
    myidx = nxt;
    dv = ndv;
  }
  const float4 b0 = *(const float4*)(bias + lane * 8);
  const float4 b1 = *(const float4*)(bias + lane * 8 + 4);
  acc[0] = fmaxf(acc[0] + b0.x, 0.f);
  acc[1] = fmaxf(acc[1] + b0.y, 0.f);
  acc[2] = fmaxf(acc[2] + b0.z, 0.f);
  acc[3] = fmaxf(acc[3] + b0.w, 0.f);
  acc[4] = fmaxf(acc[4] + b1.x, 0.f);
  acc[5] = fmaxf(acc[5] + b1.y, 0.f);
  acc[6] = fmaxf(acc[6] + b1.z, 0.f);
  acc[7] = fmaxf(acc[7] + b1.w, 0.f);
}

// layer-1 aggregation: store h1 bf16
__global__ __launch_bounds__(256) void gather_k(const u16* __restrict__ xw,
                                                u16* __restrict__ hout,
                                                const int* __restrict__ rowptr,
                                                const int* __restrict__ counts,
                                                const int* __restrict__ csr,
                                                const float* __restrict__ dinv,
                                                const float* __restrict__ bias, int n) {
  int idx = blockIdx.x * 256 + threadIdx.x;
  int nid = idx >> 3;
  int lane = idx & 7;
  if (nid >= n) return;
  float acc[8];
  gather_node(xw, rowptr, counts, csr, dinv, bias, nid, lane, acc);
  uint4 o;
  o.x = ((u32)f2bf(acc[0])) | ((u32)f2bf(acc[1]) << 16);
  o.y = ((u32)f2bf(acc[2])) | ((u32)f2bf(acc[3]) << 16);
  o.z = ((u32)f2bf(acc[4])) | ((u32)f2bf(acc[5]) << 16);
  o.w = ((u32)f2bf(acc[6])) | ((u32)f2bf(acc[7]) << 16);
  *(uint4*)(hout + (size_t)nid * 64 + lane * 8) = o;
}

// layer-2 aggregation fused with pooling: h2 never materialized.
__global__ __launch_bounds__(256) void gpool_k(const u16* __restrict__ xw,
                                               const int* __restrict__ rowptr,
                                               const int* __restrict__ counts,
                                               const int* __restrict__ csr,
                                               const float* __restrict__ dinv,
                                               const float* __restrict__ bias,
                                               const int* __restrict__ batch,
                                               float* __restrict__ gsum,
                                               u32* __restrict__ gmax, int n) {
  __shared__ float lsum[2][64];
  __shared__ u32 lmax[2][64];
  int t = threadIdx.x;
  if (t < 128) { lsum[t >> 6][t & 63] = 0.f; lmax[t >> 6][t & 63] = 0u; }
  __syncthreads();
  int idx = blockIdx.x * 256 + t;
  int nid = idx >> 3;
  int lane = idx & 7;
  bool active = nid < n;
  int nid0 = (blockIdx.x * 256) >> 3;
  int gfirst = batch[nid0 < n ? nid0 : (n - 1)];
  float acc[8] = {0.f, 0.f, 0.f, 0.f, 0.f, 0.f, 0.f, 0.f};
  int g = gfirst;
  if (active) {
    gather_node(xw, rowptr, counts, csr, dinv, bias, nid, lane, acc);
    g = batch[nid];
  }
  int gloc = g - gfirst;
  if (active) {
    if (gloc < 2) {
      #pragma unroll
      for (int i = 0; i < 8; i++) {
        atomicAdd(&lsum[gloc][lane * 8 + i], acc[i]);
        atomicMax(&lmax[gloc][lane * 8 + i], __float_as_uint(acc[i]));
      }
    } else {  // rare fallback: block spans >2 graphs
      #pragma unroll
      for (int i = 0; i < 8; i++) {
        atomicAdd(&gsum[g * 64 + lane * 8 + i], acc[i]);
        atomicMax(&gmax[g * 64 + lane * 8 + i], __float_as_uint(acc[i]));
      }
    }
  }
  __syncthreads();
  if (t < 128) {
    int gl = t >> 6, f = t & 63;
    int gg = gfirst + gl;
    if (gg < NG) {
      float s = lsum[gl][f];
      u32 m = lmax[gl][f];
      if (s != 0.f) atomicAdd(&gsum[gg * 64 + f], s);
      if (m) atomicMax(&gmax[gg * 64 + f], m);
    }
  }
}

// ================= finalize: xcat + head =================

__global__ __launch_bounds__(64) void fin_k(const float* __restrict__ gsum,
                                            const u32* __restrict__ gmax,
                                            const int* __restrict__ batch, int n,
                                            const float* __restrict__ Wlin,
                                            const float* __restrict__ blin,
                                            float* __restrict__ xcat,
                                            float* __restrict__ outh) {
  int g = blockIdx.x;
  int lane = threadIdx.x;
  __shared__ int se[2];
  if (lane < 2) {
    int target = g + lane;
    int lo = 0, hi = n;
    while (lo < hi) {
      int mid = (lo + hi) >> 1;
      if (batch[mid] < target) lo = mid + 1; else hi = mid;
    }
    se[lane] = lo;
  }
  __syncthreads();
  int cnt = se[1] - se[0];
  float x0 = gsum[g * 64 + lane];
  float x1 = x0 / fmaxf((float)cnt, 1.0f);
  float x2 = __uint_as_float(gmax[g * 64 + lane]);
  xcat[g * CAT + lane]       = x0;
  xcat[g * CAT + 64 + lane]  = x1;
  xcat[g * CAT + 128 + lane] = x2;
  #pragma unroll
  for (int o = 0; o < 2; o++) {
    float p = x0 * Wlin[lane * 2 + o] +
              x1 * Wlin[(64 + lane) * 2 + o] +
              x2 * Wlin[(128 + lane) * 2 + o];
    #pragma unroll
    for (int off = 32; off > 0; off >>= 1) p += __shfl_down(p, off, 64);
    if (lane == 0) outh[g * 2 + o] = p + blin[o];
  }
}

// ================= launch =================

extern "C" void kernel_launch(void* const* d_in, const int* in_sizes, int n_in,
                              void* d_out, int out_size, void* d_ws, size_t ws_size,
                              hipStream_t stream) {
  const float* x    = (const float*)d_in[0];
  const float* W1   = (const float*)d_in[1];
  const float* b1   = (const float*)d_in[2];
  const float* W2   = (const float*)d_in[3];
  const float* b2   = (const float*)d_in[4];
  const float* Wlin = (const float*)d_in[5];
  const float* blin = (const float*)d_in[6];
  const int*   ei   = (const int*)d_in[7];
  const int*   batch= (const int*)d_in[8];

  const int N = in_sizes[0] / IN_F;      // 100000
  const int E = in_sizes[7] / 2;         // 1600000
  const int* src = ei;
  const int* dst = ei + E;
  const int ndig = (N + 511) >> 9;       // 196
  const int nbE  = (E + 4095) / 4096;    // 391

  char* w = (char*)d_ws;
  auto alloc = [&](size_t bytes) {
    void* p = (void*)w;
    w += (bytes + 255) & ~(size_t)255;
    return p;
  };
  int*   rowptr = (int*)alloc((size_t)N * 4);
  int*   counts = (int*)alloc((size_t)N * 4);
  float* dinv   = (float*)alloc((size_t)N * 4);
  int*   csr    = (int*)alloc((size_t)ndig * DCAP * 4);
  int*   zbuf   = (int*)alloc((size_t)(256 + 2 * NG * 64) * 4);  // gcur | gsum | gmax
  u16*   bufA   = (u16*)alloc((size_t)N * 64 * 2);
  u16*   bufB   = (u16*)alloc((size_t)N * 64 * 2);
  u32*   stage  = (u32*)alloc((size_t)ndig * DCAP * 4);

  int*   gcur = zbuf;
  float* gsum = (float*)(zbuf + 256);
  u32*   gmax = (u32*)(zbuf + 256 + NG * 64);

  float* xcat = (float*)d_out;
  float* outh = (float*)d_out + NG * CAT;

  const int nz = 256 + 2 * NG * 64;
  zero_k  <<<(nz + 255) / 256, 256, 0, stream>>>(zbuf, nz);
  stage_k <<<nbE, 256, 0, stream>>>(src, dst, E, gcur, stage, ndig);
  csr_k   <<<ndig, 256, 0, stream>>>(stage, gcur, rowptr, counts, dinv, csr, N);

  // layer 1
  gemm_mfma_k<IN_F, false> <<<(N + 63) / 64, 256, 0, stream>>>(x, W1, bufA, N);
  gather_k <<<(N * 8 + 255) / 256, 256, 0, stream>>>(bufA, bufB, rowptr, counts, csr, dinv, b1, N);

  // layer 2 (gemm) then fused aggregation+pool
  gemm_mfma_k<C1, true> <<<(N + 63) / 64, 256, 0, stream>>>(bufB, W2, bufA, N);
  gpool_k <<<(N * 8 + 255) / 256, 256, 0, stream>>>(bufA, rowptr, counts, csr, dinv, b2,
                                                    batch, gsum, gmax, N);

  // finalize: xcat + head
  fin_k <<<NG, 64, 0, stream>>>(gsum, gmax, batch, N, Wlin, blin, xcat, outh);
}

// Round 9
// 166.549 us; speedup vs baseline: 1.0807x; 1.0807x over previous
//
#include <hip/hip_runtime.h>

#define IN_F 128
#define C1 64
#define NG 128
#define CAT 192
#define DCAP 10240   // per-digit edge capacity (mean 8163, sigma ~90)

typedef unsigned short u16;
typedef unsigned int u32;
typedef __attribute__((ext_vector_type(8))) short bf16x8;
typedef __attribute__((ext_vector_type(4))) float f32x4;

__device__ inline u16 f2bf(float f) {
  u32 u = __float_as_uint(f);
  u = (u + 0x7FFFu + ((u >> 16) & 1u)) >> 16;   // RTNE
  return (u16)u;
}
__device__ inline float bf2f(u16 h) { return __uint_as_float(((u32)h) << 16); }
__device__ inline float bflo(u32 p) { return __uint_as_float(p << 16); }
__device__ inline float bfhi(u32 p) { return __uint_as_float(p & 0xFFFF0000u); }

// ================= zero scratch =================

__global__ void zero_k(int* __restrict__ g, int n) {
  int i = blockIdx.x * 256 + threadIdx.x;
  if (i < n) g[i] = 0;
}

// ================= CSR build (bucketed, u32-packed stage) =================

__global__ __launch_bounds__(256) void stage_k(const int* __restrict__ src,
                                               const int* __restrict__ dst, int e,
                                               int* __restrict__ gcur,
                                               u32* __restrict__ stage, int ndig) {
  __shared__ int h[256];
  __shared__ int cur[256];
  int t = threadIdx.x;
  h[t] = 0;
  __syncthreads();
  int base = blockIdx.x * 4096;
  int mys[16], myd[16];
  #pragma unroll
  for (int i = 0; i < 16; i++) {
    int j = base + t + i * 256;
    if (j < e) {
      mys[i] = src[j];
      myd[i] = dst[j];
      atomicAdd(&h[myd[i] >> 9], 1);
    } else {
      myd[i] = -1;
    }
  }
  __syncthreads();
  int cnt = h[t];
  __syncthreads();
  int gbase = 0;
  if (t < ndig && cnt > 0) gbase = atomicAdd(&gcur[t], cnt);
  h[t] = gbase;
  cur[t] = 0;
  __syncthreads();
  #pragma unroll
  for (int i = 0; i < 16; i++) {
    if (myd[i] >= 0) {
      int d = myd[i] >> 9;
      int r = atomicAdd(&cur[d], 1);
      stage[(size_t)d * DCAP + h[d] + r] = (u32)mys[i] | ((u32)(myd[i] & 511) << 17);
    }
  }
}

__global__ __launch_bounds__(256) void csr_k(const u32* __restrict__ stage,
                                             const int* __restrict__ gcur,
                                             int* __restrict__ rowptr,
                                             int* __restrict__ counts,
                                             float* __restrict__ dinv,
                                             int* __restrict__ csr, int n) {
  __shared__ int hc[512];
  __shared__ int hb[512];
  __shared__ int cu[512];
  __shared__ int sc[256];
  int dg = blockIdx.x;
  int t = threadIdx.x;
  int n0 = dg * 512;
  int nloc = min(n - n0, 512);
  int e0 = dg * DCAP;
  int e1 = e0 + gcur[dg];
  hc[t] = 0; hc[t + 256] = 0;
  __syncthreads();
  for (int j = e0 + t; j < e1; j += 256) atomicAdd(&hc[stage[j] >> 17], 1);
  __syncthreads();
  int a0 = hc[2 * t], a1 = hc[2 * t + 1];
  int s = a0 + a1;
  sc[t] = s;
  __syncthreads();
  #pragma unroll
  for (int off = 1; off < 256; off <<= 1) {
    int x = sc[t] + ((t >= off) ? sc[t - off] : 0);
    __syncthreads();
    sc[t] = x;
    __syncthreads();
  }
  int excl = sc[t] - s;
  hb[2 * t] = excl;
  hb[2 * t + 1] = excl + a0;
  cu[2 * t] = 0; cu[2 * t + 1] = 0;
  __syncthreads();
  for (int i = t; i < nloc; i += 256) {
    int node = n0 + i;
    rowptr[node] = e0 + hb[i];
    counts[node] = hc[i];
    dinv[node] = rsqrtf((float)hc[i] + 1.0f);  // +1 self loop
  }
  __syncthreads();
  for (int j = e0 + t; j < e1; j += 256) {
    u32 p = stage[j];
    int li = p >> 17;
    int r = atomicAdd(&cu[li], 1);
    csr[e0 + hb[li] + r] = (int)(p & 0x1FFFFu);
  }
}

// ================= MFMA GEMM  Y[N,64](bf16) = X[N,K] @ W[K,64] =================

template <int K, bool IN_BF16>
__global__ __launch_bounds__(256) void gemm_mfma_k(const void* __restrict__ Xv,
                                                   const float* __restrict__ W,
                                                   u16* __restrict__ Y, int n) {
  constexpr int KK = K / 32;
  constexpr int XSN = 2048 * KK;
  constexpr int TOT = 4096 * KK;
  constexpr int SMEMN = (TOT > 9216) ? TOT : 9216;
  __shared__ u16 smem[SMEMN];
  u16* Xs = smem;
  u16* Ws = smem + XSN;
  int t = threadIdx.x;
  int row0 = blockIdx.x * 64;

  for (int idx = t; idx < K * 16; idx += 256) {
    int k = idx >> 4, c4 = (idx & 15) * 4;
    float4 wv = *(const float4*)(W + (size_t)k * 64 + c4);
    int kk = k >> 5, k8 = (k & 31) >> 3, kr = k & 7;
    float wa[4] = {wv.x, wv.y, wv.z, wv.w};
    #pragma unroll
    for (int j = 0; j < 4; j++) {
      int c = c4 + j;
      u32 byte = (u32)(((kk * 64 + c) * 32 + k8 * 8 + kr) * 2);
      byte ^= (u32)((c & 7) << 4);
      *(u16*)((char*)Ws + byte) = f2bf(wa[j]);
    }
  }

  for (int idx = t; idx < 8 * K; idx += 256) {
    int r = idx / (K / 8);
    int c8 = idx % (K / 8);
    int gr = row0 + r;
    u16 vals[8];
    if (gr < n) {
      if (IN_BF16) {
        *(uint4*)vals = *(const uint4*)((const u16*)Xv + (size_t)gr * K + c8 * 8);
      } else {
        const float4 x0 = *(const float4*)((const float*)Xv + (size_t)gr * K + c8 * 8);
        const float4 x1 = *(const float4*)((const float*)Xv + (size_t)gr * K + c8 * 8 + 4);
        vals[0] = f2bf(x0.x); vals[1] = f2bf(x0.y); vals[2] = f2bf(x0.z); vals[3] = f2bf(x0.w);
        vals[4] = f2bf(x1.x); vals[5] = f2bf(x1.y); vals[6] = f2bf(x1.z); vals[7] = f2bf(x1.w);
      }
    } else {
      #pragma unroll
      for (int j = 0; j < 8; j++) vals[j] = 0;
    }
    int wrow = r >> 4, row = r & 15, kk = c8 >> 2, k8 = c8 & 3;
    u32 byte = (u32)((((wrow * KK + kk) * 16 + row) * 32 + k8 * 8) * 2);
    byte ^= (u32)((row & 7) << 4);
    *(uint4*)((char*)Xs + byte) = *(uint4*)vals;
  }
  __syncthreads();

  int w = t >> 6, l = t & 63;
  int lrow = l & 15, lk = l >> 4;
  bf16x8 bfrag[KK][4];
  #pragma unroll
  for (int kk = 0; kk < KK; kk++) {
    #pragma unroll
    for (int cb = 0; cb < 4; cb++) {
      int col = cb * 16 + lrow;
      u32 byte = (u32)(((kk * 64 + col) * 32 + lk * 8) * 2);
      byte ^= (u32)((col & 7) << 4);
      bfrag[kk][cb] = *(bf16x8*)((char*)Ws + byte);
    }
  }
  f32x4 acc[4] = {};
  #pragma unroll
  for (int kk = 0; kk < KK; kk++) {
    u32 abyte = (u32)((((w * KK + kk) * 16 + lrow) * 32 + lk * 8) * 2);
    abyte ^= (u32)((lrow & 7) << 4);
    bf16x8 a = *(bf16x8*)((char*)Xs + abyte);
    #pragma unroll
    for (int cb = 0; cb < 4; cb++) {
      acc[cb] = __builtin_amdgcn_mfma_f32_16x16x32_bf16(a, bfrag[kk][cb], acc[cb], 0, 0, 0);
    }
  }
  __syncthreads();

  #pragma unroll
  for (int cb = 0; cb < 4; cb++) {
    #pragma unroll
    for (int reg = 0; reg < 4; reg++) {
      int r = w * 16 + lk * 4 + reg;
      int c = cb * 16 + lrow;
      smem[r * 72 + c] = f2bf(acc[cb][reg]);
    }
  }
  __syncthreads();
  #pragma unroll
  for (int p = 0; p < 2; p++) {
    int idx = t + p * 256;
    int rr = idx >> 3, ch = idx & 7;
    int gr = row0 + rr;
    if (gr < n) {
      uint4 v = *(uint4*)&smem[rr * 72 + ch * 8];
      *(uint4*)(Y + (size_t)gr * 64 + ch * 8) = v;
    }
  }
}

// ================= gather core =================

__device__ __forceinline__ void gather_node(const u16* __restrict__ xw,
                                            const int* __restrict__ rowptr,
                                            const int* __restrict__ counts,
                                            const int* __restrict__ csr,
                                            const float* __restrict__ dinv,
                                            const float* __restrict__ bias,
                                            int nid, int lane, float acc[8]) {
  float di = dinv[nid];
  float sc = di * di;
  {
    uint4 a = *(const uint4*)(xw + (size_t)nid * 64 + lane * 8);
    acc[0] = bflo(a.x) * sc; acc[1] = bfhi(a.x) * sc;
    acc[2] = bflo(a.y) * sc; acc[3] = bfhi(a.y) * sc;
    acc[4] = bflo(a.z) * sc; acc[5] = bfhi(a.z) * sc;
    acc[6] = bflo(a.w) * sc; acc[7] = bfhi(a.w) * sc;
  }
  int st = rowptr[nid];
  int cn = counts[nid];
  int myidx = 0;
  float dv = 0.f;
  if (lane < cn) {
    myidx = csr[st + lane];
    dv = dinv[myidx];
  }
  for (int c = 0; c < cn; c += 8) {
    int rem = cn - c;
    uint4 vv[8];
    #pragma unroll
    for (int i = 0; i < 8; i++) {
      int s = __shfl(myidx, i, 8);
      if (i < rem) {
        vv[i] = *(const uint4*)(xw + (size_t)s * 64 + lane * 8);
      } else {
        vv[i] = make_uint4(0, 0, 0, 0);
      }
    }
    float ww[8];
    float myw = dv * di;
    #pragma unroll
    for (int i = 0; i < 8; i++) ww[i] = (i < rem) ? __shfl(myw, i, 8) : 0.f;
    int nxt = 0;
    float ndv = 0.f;
    if (c + 8 < cn && lane < rem - 8) {
      nxt = csr[st + c + 8 + lane];
      ndv = dinv[nxt];
    }
    #pragma unroll
    for (int i = 0; i < 8; i++) {
      float wgt = ww[i];
      acc[0] += bflo(vv[i].x) * wgt; acc[1] += bfhi(vv[i].x) * wgt;
      acc[2] += bflo(vv[i].y) * wgt; acc[3] += bfhi(vv[i].y) * wgt;
      acc[4] += bflo(vv[i].z) * wgt; acc[5] += bfhi(vv[i].z) * wgt;
      acc[6] += bflo(vv[i].w) * wgt; acc[7] += bfhi(vv[i].w) * wgt;
    }
    myidx = nxt;
    dv = ndv;
  }
  const float4 b0 = *(const float4*)(bias + lane * 8);
  const float4 b1 = *(const float4*)(bias + lane * 8 + 4);
  acc[0] = fmaxf(acc[0] + b0.x, 0.f);
  acc[1] = fmaxf(acc[1] + b0.y, 0.f);
  acc[2] = fmaxf(acc[2] + b0.z, 0.f);
  acc[3] = fmaxf(acc[3] + b0.w, 0.f);
  acc[4] = fmaxf(acc[4] + b1.x, 0.f);
  acc[5] = fmaxf(acc[5] + b1.y, 0.f);
  acc[6] = fmaxf(acc[6] + b1.z, 0.f);
  acc[7] = fmaxf(acc[7] + b1.w, 0.f);
}

// layer-1 aggregation: store h1 bf16
__global__ __launch_bounds__(256) void gather_k(const u16* __restrict__ xw,
                                                u16* __restrict__ hout,
                                                const int* __restrict__ rowptr,
                                                const int* __restrict__ counts,
                                                const int* __restrict__ csr,
                                                const float* __restrict__ dinv,
                                                const float* __restrict__ bias, int n) {
  int idx = blockIdx.x * 256 + threadIdx.x;
  int nid = idx >> 3;
  int lane = idx & 7;
  if (nid >= n) return;
  float acc[8];
  gather_node(xw, rowptr, counts, csr, dinv, bias, nid, lane, acc);
  uint4 o;
  o.x = ((u32)f2bf(acc[0])) | ((u32)f2bf(acc[1]) << 16);
  o.y = ((u32)f2bf(acc[2])) | ((u32)f2bf(acc[3]) << 16);
  o.z = ((u32)f2bf(acc[4])) | ((u32)f2bf(acc[5]) << 16);
  o.w = ((u32)f2bf(acc[6])) | ((u32)f2bf(acc[7]) << 16);
  *(uint4*)(hout + (size_t)nid * 64 + lane * 8) = o;
}

// layer-2 aggregation fused with pooling; shuffle-tree reduction, no LDS atomics.
__global__ __launch_bounds__(256) void gpool_k(const u16* __restrict__ xw,
                                               const int* __restrict__ rowptr,
                                               const int* __restrict__ counts,
                                               const int* __restrict__ csr,
                                               const float* __restrict__ dinv,
                                               const float* __restrict__ bias,
                                               const int* __restrict__ batch,
                                               float* __restrict__ gsum,
                                               u32* __restrict__ gmax, int n) {
  __shared__ float wlsum[4][2][64];  // per-wave, per-local-graph slots
  __shared__ float wlmax[4][2][64];
  int t = threadIdx.x;
  {  // zero 512 floats per array (2 per thread)
    ((float*)wlsum)[t] = 0.f; ((float*)wlsum)[t + 256] = 0.f;
    ((float*)wlmax)[t] = 0.f; ((float*)wlmax)[t + 256] = 0.f;
  }
  __syncthreads();
  int idx = blockIdx.x * 256 + t;
  int nid = idx >> 3;
  int lane = idx & 7;
  int wv = t >> 6;
  bool active = nid < n;
  int g = batch[active ? nid : (n - 1)];
  float acc[8] = {0.f, 0.f, 0.f, 0.f, 0.f, 0.f, 0.f, 0.f};
  if (active) gather_node(xw, rowptr, counts, csr, dinv, bias, nid, lane, acc);

  int nid0 = (blockIdx.x * 256) >> 3;
  int gfirst = batch[nid0 < n ? nid0 : (n - 1)];
  int g0 = __shfl(g, 0, 64);
  bool uni = (__ballot(g == g0) == ~0ull);
  int gloc = g0 - gfirst;

  if (uni && gloc >= 0 && gloc < 2) {
    // butterfly over the 8 node-groups of the wave (stride 8,16,32)
    float m[8];
    #pragma unroll
    for (int i = 0; i < 8; i++) m[i] = acc[i];
    #pragma unroll
    for (int d = 8; d <= 32; d <<= 1) {
      #pragma unroll
      for (int i = 0; i < 8; i++) {
        acc[i] += __shfl_down(acc[i], d, 64);
        m[i] = fmaxf(m[i], __shfl_down(m[i], d, 64));
      }
    }
    if ((t & 63) < 8) {  // lane==t&7 holds totals for features lane*8..+7
      #pragma unroll
      for (int i = 0; i < 8; i++) {
        wlsum[wv][gloc][lane * 8 + i] = acc[i];
        wlmax[wv][gloc][lane * 8 + i] = m[i];
      }
    }
  } else if (active) {
    // rare: wave spans graph boundary (or >2 graphs in block)
    #pragma unroll
    for (int i = 0; i < 8; i++) {
      atomicAdd(&gsum[g * 64 + lane * 8 + i], acc[i]);
      atomicMax(&gmax[g * 64 + lane * 8 + i], __float_as_uint(acc[i]));
    }
  }
  __syncthreads();
  if (t < 128) {
    int gl = t >> 6, f = t & 63;
    int gg = gfirst + gl;
    if (gg < NG) {
      float s = wlsum[0][gl][f] + wlsum[1][gl][f] + wlsum[2][gl][f] + wlsum[3][gl][f];
      float m = fmaxf(fmaxf(wlmax[0][gl][f], wlmax[1][gl][f]),
                      fmaxf(wlmax[2][gl][f], wlmax[3][gl][f]));
      if (s != 0.f) atomicAdd(&gsum[gg * 64 + f], s);
      if (m > 0.f) atomicMax(&gmax[gg * 64 + f], __float_as_uint(m));
    }
  }
}

// ================= finalize: xcat + head =================

__global__ __launch_bounds__(64) void fin_k(const float* __restrict__ gsum,
                                            const u32* __restrict__ gmax,
                                            const int* __restrict__ batch, int n,
                                            const float* __restrict__ Wlin,
                                            const float* __restrict__ blin,
                                            float* __restrict__ xcat,
                                            float* __restrict__ outh) {
  int g = blockIdx.x;
  int lane = threadIdx.x;
  __shared__ int se[2];
  if (lane < 2) {
    int target = g + lane;
    int lo = 0, hi = n;
    while (lo < hi) {
      int mid = (lo + hi) >> 1;
      if (batch[mid] < target) lo = mid + 1; else hi = mid;
    }
    se[lane] = lo;
  }
  __syncthreads();
  int cnt = se[1] - se[0];
  float x0 = gsum[g * 64 + lane];
  float x1 = x0 / fmaxf((float)cnt, 1.0f);
  float x2 = __uint_as_float(gmax[g * 64 + lane]);
  xcat[g * CAT + lane]       = x0;
  xcat[g * CAT + 64 + lane]  = x1;
  xcat[g * CAT + 128 + lane] = x2;
  #pragma unroll
  for (int o = 0; o < 2; o++) {
    float p = x0 * Wlin[lane * 2 + o] +
              x1 * Wlin[(64 + lane) * 2 + o] +
              x2 * Wlin[(128 + lane) * 2 + o];
    #pragma unroll
    for (int off = 32; off > 0; off >>= 1) p += __shfl_down(p, off, 64);
    if (lane == 0) outh[g * 2 + o] = p + blin[o];
  }
}

// ================= launch =================

extern "C" void kernel_launch(void* const* d_in, const int* in_sizes, int n_in,
                              void* d_out, int out_size, void* d_ws, size_t ws_size,
                              hipStream_t stream) {
  const float* x    = (const float*)d_in[0];
  const float* W1   = (const float*)d_in[1];
  const float* b1   = (const float*)d_in[2];
  const float* W2   = (const float*)d_in[3];
  const float* b2   = (const float*)d_in[4];
  const float* Wlin = (const float*)d_in[5];
  const float* blin = (const float*)d_in[6];
  const int*   ei   = (const int*)d_in[7];
  const int*   batch= (const int*)d_in[8];

  const int N = in_sizes[0] / IN_F;      // 100000
  const int E = in_sizes[7] / 2;         // 1600000
  const int* src = ei;
  const int* dst = ei + E;
  const int ndig = (N + 511) >> 9;       // 196
  const int nbE  = (E + 4095) / 4096;    // 391

  char* w = (char*)d_ws;
  auto alloc = [&](size_t bytes) {
    void* p = (void*)w;
    w += (bytes + 255) & ~(size_t)255;
    return p;
  };
  int*   rowptr = (int*)alloc((size_t)N * 4);
  int*   counts = (int*)alloc((size_t)N * 4);
  float* dinv   = (float*)alloc((size_t)N * 4);
  int*   csr    = (int*)alloc((size_t)ndig * DCAP * 4);
  int*   zbuf   = (int*)alloc((size_t)(256 + 2 * NG * 64) * 4);  // gcur | gsum | gmax
  u16*   bufA   = (u16*)alloc((size_t)N * 64 * 2);
  u16*   bufB   = (u16*)alloc((size_t)N * 64 * 2);
  u32*   stage  = (u32*)alloc((size_t)ndig * DCAP * 4);

  int*   gcur = zbuf;
  float* gsum = (float*)(zbuf + 256);
  u32*   gmax = (u32*)(zbuf + 256 + NG * 64);

  float* xcat = (float*)d_out;
  float* outh = (float*)d_out + NG * CAT;

  const int nz = 256 + 2 * NG * 64;
  zero_k  <<<(nz + 255) / 256, 256, 0, stream>>>(zbuf, nz);
  stage_k <<<nbE, 256, 0, stream>>>(src, dst, E, gcur, stage, ndig);
  csr_k   <<<ndig, 256, 0, stream>>>(stage, gcur, rowptr, counts, dinv, csr, N);

  // layer 1
  gemm_mfma_k<IN_F, false> <<<(N + 63) / 64, 256, 0, stream>>>(x, W1, bufA, N);
  gather_k <<<(N * 8 + 255) / 256, 256, 0, stream>>>(bufA, bufB, rowptr, counts, csr, dinv, b1, N);

  // layer 2 (gemm) then fused aggregation+pool
  gemm_mfma_k<C1, true> <<<(N + 63) / 64, 256, 0, stream>>>(bufB, W2, bufA, N);
  gpool_k <<<(N * 8 + 255) / 256, 256, 0, stream>>>(bufA, rowptr, counts, csr, dinv, b2,
                                                    batch, gsum, gmax, N);

  // finalize: xcat + head
  fin_k <<<NG, 64, 0, stream>>>(gsum, gmax, batch, N, Wlin, blin, xcat, outh);
}

// Round 10
// 159.164 us; speedup vs baseline: 1.1308x; 1.0464x over previous
//
#include <hip/hip_runtime.h>

#define IN_F 128
#define C1 64
#define NG 128
#define CAT 192
#define DCAP 10240   // per-digit edge capacity (mean 8163, sigma ~90)

typedef unsigned short u16;
typedef unsigned int u32;
typedef __attribute__((ext_vector_type(8))) short bf16x8;
typedef __attribute__((ext_vector_type(4))) float f32x4;

__device__ inline u16 f2bf(float f) {
  u32 u = __float_as_uint(f);
  u = (u + 0x7FFFu + ((u >> 16) & 1u)) >> 16;   // RTNE
  return (u16)u;
}
__device__ inline float bf2f(u16 h) { return __uint_as_float(((u32)h) << 16); }
__device__ inline float bflo(u32 p) { return __uint_as_float(p << 16); }
__device__ inline float bfhi(u32 p) { return __uint_as_float(p & 0xFFFF0000u); }

// ================= zero scratch =================

__global__ void zero_k(int* __restrict__ g, int n) {
  int i = blockIdx.x * 256 + threadIdx.x;
  if (i < n) g[i] = 0;
}

// ================= CSR build (bucketed, u32-packed stage) =================

__global__ __launch_bounds__(256) void stage_k(const int* __restrict__ src,
                                               const int* __restrict__ dst, int e,
                                               int* __restrict__ gcur,
                                               u32* __restrict__ stage, int ndig) {
  __shared__ int h4[4][256];  // per-wave histograms (cuts LDS same-addr atomic serialization)
  __shared__ int h[256];
  __shared__ int cur[256];
  int t = threadIdx.x;
  int wv = t >> 6;
  h4[0][t] = 0; h4[1][t] = 0; h4[2][t] = 0; h4[3][t] = 0;
  __syncthreads();
  int base = blockIdx.x * 4096;
  int mys[16], myd[16];
  #pragma unroll
  for (int i = 0; i < 16; i++) {
    int j = base + t + i * 256;
    if (j < e) {
      mys[i] = src[j];
      myd[i] = dst[j];
      atomicAdd(&h4[wv][myd[i] >> 9], 1);
    } else {
      myd[i] = -1;
    }
  }
  __syncthreads();
  int cnt = h4[0][t] + h4[1][t] + h4[2][t] + h4[3][t];
  int gbase = 0;
  if (t < ndig && cnt > 0) gbase = atomicAdd(&gcur[t], cnt);
  h[t] = gbase;
  cur[t] = 0;
  __syncthreads();
  #pragma unroll
  for (int i = 0; i < 16; i++) {
    if (myd[i] >= 0) {
      int d = myd[i] >> 9;
      int r = atomicAdd(&cur[d], 1);
      stage[(size_t)d * DCAP + h[d] + r] = (u32)mys[i] | ((u32)(myd[i] & 511) << 17);
    }
  }
}

__global__ __launch_bounds__(256) void csr_k(const u32* __restrict__ stage,
                                             const int* __restrict__ gcur,
                                             int* __restrict__ rowptr,
                                             int* __restrict__ counts,
                                             float* __restrict__ dinv,
                                             int* __restrict__ csr, int n) {
  __shared__ int hc[512];
  __shared__ int hb[512];
  __shared__ int cu[512];
  __shared__ int sc[256];
  int dg = blockIdx.x;
  int t = threadIdx.x;
  int n0 = dg * 512;
  int nloc = min(n - n0, 512);
  int e0 = dg * DCAP;
  int e1 = e0 + gcur[dg];
  hc[t] = 0; hc[t + 256] = 0;
  __syncthreads();
  for (int j = e0 + t; j < e1; j += 256) atomicAdd(&hc[stage[j] >> 17], 1);
  __syncthreads();
  int a0 = hc[2 * t], a1 = hc[2 * t + 1];
  int s = a0 + a1;
  sc[t] = s;
  __syncthreads();
  #pragma unroll
  for (int off = 1; off < 256; off <<= 1) {
    int x = sc[t] + ((t >= off) ? sc[t - off] : 0);
    __syncthreads();
    sc[t] = x;
    __syncthreads();
  }
  int excl = sc[t] - s;
  hb[2 * t] = excl;
  hb[2 * t + 1] = excl + a0;
  cu[2 * t] = 0; cu[2 * t + 1] = 0;
  __syncthreads();
  for (int i = t; i < nloc; i += 256) {
    int node = n0 + i;
    rowptr[node] = e0 + hb[i];
    counts[node] = hc[i];
    dinv[node] = rsqrtf((float)hc[i] + 1.0f);  // +1 self loop
  }
  __syncthreads();
  for (int j = e0 + t; j < e1; j += 256) {
    u32 p = stage[j];
    int li = p >> 17;
    int r = atomicAdd(&cu[li], 1);
    csr[e0 + hb[li] + r] = (int)(p & 0x1FFFFu);
  }
}

// ================= MFMA GEMM  Y[N,64](bf16) = X[N,K] @ W[K,64] =================

template <int K, bool IN_BF16>
__global__ __launch_bounds__(256) void gemm_mfma_k(const void* __restrict__ Xv,
                                                   const float* __restrict__ W,
                                                   u16* __restrict__ Y, int n) {
  constexpr int KK = K / 32;
  constexpr int XSN = 2048 * KK;
  constexpr int TOT = 4096 * KK;
  constexpr int SMEMN = (TOT > 9216) ? TOT : 9216;
  __shared__ u16 smem[SMEMN];
  u16* Xs = smem;
  u16* Ws = smem + XSN;
  int t = threadIdx.x;
  int row0 = blockIdx.x * 64;

  for (int idx = t; idx < K * 16; idx += 256) {
    int k = idx >> 4, c4 = (idx & 15) * 4;
    float4 wv = *(const float4*)(W + (size_t)k * 64 + c4);
    int kk = k >> 5, k8 = (k & 31) >> 3, kr = k & 7;
    float wa[4] = {wv.x, wv.y, wv.z, wv.w};
    #pragma unroll
    for (int j = 0; j < 4; j++) {
      int c = c4 + j;
      u32 byte = (u32)(((kk * 64 + c) * 32 + k8 * 8 + kr) * 2);
      byte ^= (u32)((c & 7) << 4);
      *(u16*)((char*)Ws + byte) = f2bf(wa[j]);
    }
  }

  for (int idx = t; idx < 8 * K; idx += 256) {
    int r = idx / (K / 8);
    int c8 = idx % (K / 8);
    int gr = row0 + r;
    u16 vals[8];
    if (gr < n) {
      if (IN_BF16) {
        *(uint4*)vals = *(const uint4*)((const u16*)Xv + (size_t)gr * K + c8 * 8);
      } else {
        const float4 x0 = *(const float4*)((const float*)Xv + (size_t)gr * K + c8 * 8);
        const float4 x1 = *(const float4*)((const float*)Xv + (size_t)gr * K + c8 * 8 + 4);
        vals[0] = f2bf(x0.x); vals[1] = f2bf(x0.y); vals[2] = f2bf(x0.z); vals[3] = f2bf(x0.w);
        vals[4] = f2bf(x1.x); vals[5] = f2bf(x1.y); vals[6] = f2bf(x1.z); vals[7] = f2bf(x1.w);
      }
    } else {
      #pragma unroll
      for (int j = 0; j < 8; j++) vals[j] = 0;
    }
    int wrow = r >> 4, row = r & 15, kk = c8 >> 2, k8 = c8 & 3;
    u32 byte = (u32)((((wrow * KK + kk) * 16 + row) * 32 + k8 * 8) * 2);
    byte ^= (u32)((row & 7) << 4);
    *(uint4*)((char*)Xs + byte) = *(uint4*)vals;
  }
  __syncthreads();

  int w = t >> 6, l = t & 63;
  int lrow = l & 15, lk = l >> 4;
  bf16x8 bfrag[KK][4];
  #pragma unroll
  for (int kk = 0; kk < KK; kk++) {
    #pragma unroll
    for (int cb = 0; cb < 4; cb++) {
      int col = cb * 16 + lrow;
      u32 byte = (u32)(((kk * 64 + col) * 32 + lk * 8) * 2);
      byte ^= (u32)((col & 7) << 4);
      bfrag[kk][cb] = *(bf16x8*)((char*)Ws + byte);
    }
  }
  f32x4 acc[4] = {};
  #pragma unroll
  for (int kk = 0; kk < KK; kk++) {
    u32 abyte = (u32)((((w * KK + kk) * 16 + lrow) * 32 + lk * 8) * 2);
    abyte ^= (u32)((lrow & 7) << 4);
    bf16x8 a = *(bf16x8*)((char*)Xs + abyte);
    #pragma unroll
    for (int cb = 0; cb < 4; cb++) {
      acc[cb] = __builtin_amdgcn_mfma_f32_16x16x32_bf16(a, bfrag[kk][cb], acc[cb], 0, 0, 0);
    }
  }
  __syncthreads();

  #pragma unroll
  for (int cb = 0; cb < 4; cb++) {
    #pragma unroll
    for (int reg = 0; reg < 4; reg++) {
      int r = w * 16 + lk * 4 + reg;
      int c = cb * 16 + lrow;
      smem[r * 72 + c] = f2bf(acc[cb][reg]);
    }
  }
  __syncthreads();
  #pragma unroll
  for (int p = 0; p < 2; p++) {
    int idx = t + p * 256;
    int rr = idx >> 3, ch = idx & 7;
    int gr = row0 + rr;
    if (gr < n) {
      uint4 v = *(uint4*)&smem[rr * 72 + ch * 8];
      *(uint4*)(Y + (size_t)gr * 64 + ch * 8) = v;
    }
  }
}

// ================= gather core =================

__device__ __forceinline__ void gather_node(const u16* __restrict__ xw,
                                            const int* __restrict__ rowptr,
                                            const int* __restrict__ counts,
                                            const int* __restrict__ csr,
                                            const float* __restrict__ dinv,
                                            const float* __restrict__ bias,
                                            int nid, int lane, float acc[8]) {
  float di = dinv[nid];
  float sc = di * di;
  {
    uint4 a = *(const uint4*)(xw + (size_t)nid * 64 + lane * 8);
    acc[0] = bflo(a.x) * sc; acc[1] = bfhi(a.x) * sc;
    acc[2] = bflo(a.y) * sc; acc[3] = bfhi(a.y) * sc;
    acc[4] = bflo(a.z) * sc; acc[5] = bfhi(a.z) * sc;
    acc[6] = bflo(a.w) * sc; acc[7] = bfhi(a.w) * sc;
  }
  int st = rowptr[nid];
  int cn = counts[nid];
  int myidx = 0;
  float dv = 0.f;
  if (lane < cn) {
    myidx = csr[st + lane];
    dv = dinv[myidx];
  }
  for (int c = 0; c < cn; c += 8) {
    int rem = cn - c;
    uint4 vv[8];
    #pragma unroll
    for (int i = 0; i < 8; i++) {
      int s = __shfl(myidx, i, 8);
      if (i < rem) {
        vv[i] = *(const uint4*)(xw + (size_t)s * 64 + lane * 8);
      } else {
        vv[i] = make_uint4(0, 0, 0, 0);
      }
    }
    float ww[8];
    float myw = dv * di;
    #pragma unroll
    for (int i = 0; i < 8; i++) ww[i] = (i < rem) ? __shfl(myw, i, 8) : 0.f;
    int nxt = 0;
    float ndv = 0.f;
    if (c + 8 < cn && lane < rem - 8) {
      nxt = csr[st + c + 8 + lane];
      ndv = dinv[nxt];
    }
    #pragma unroll
    for (int i = 0; i < 8; i++) {
      float wgt = ww[i];
      acc[0] += bflo(vv[i].x) * wgt; acc[1] += bfhi(vv[i].x) * wgt;
      acc[2] += bflo(vv[i].y) * wgt; acc[3] += bfhi(vv[i].y) * wgt;
      acc[4] += bflo(vv[i].z) * wgt; acc[5] += bfhi(vv[i].z) * wgt;
      acc[6] += bflo(vv[i].w) * wgt; acc[7] += bfhi(vv[i].w) * wgt;
    }
    myidx = nxt;
    dv = ndv;
  }
  const float4 b0 = *(const float4*)(bias + lane * 8);
  const float4 b1 = *(const float4*)(bias + lane * 8 + 4);
  acc[0] = fmaxf(acc[0] + b0.x, 0.f);
  acc[1] = fmaxf(acc[1] + b0.y, 0.f);
  acc[2] = fmaxf(acc[2] + b0.z, 0.f);
  acc[3] = fmaxf(acc[3] + b0.w, 0.f);
  acc[4] = fmaxf(acc[4] + b1.x, 0.f);
  acc[5] = fmaxf(acc[5] + b1.y, 0.f);
  acc[6] = fmaxf(acc[6] + b1.z, 0.f);
  acc[7] = fmaxf(acc[7] + b1.w, 0.f);
}

// layer-1 aggregation: store h1 bf16
__global__ __launch_bounds__(256) void gather_k(const u16* __restrict__ xw,
                                                u16* __restrict__ hout,
                                                const int* __restrict__ rowptr,
                                                const int* __restrict__ counts,
                                                const int* __restrict__ csr,
                                                const float* __restrict__ dinv,
                                                const float* __restrict__ bias, int n) {
  int idx = blockIdx.x * 256 + threadIdx.x;
  int nid = idx >> 3;
  int lane = idx & 7;
  if (nid >= n) return;
  float acc[8];
  gather_node(xw, rowptr, counts, csr, dinv, bias, nid, lane, acc);
  uint4 o;
  o.x = ((u32)f2bf(acc[0])) | ((u32)f2bf(acc[1]) << 16);
  o.y = ((u32)f2bf(acc[2])) | ((u32)f2bf(acc[3]) << 16);
  o.z = ((u32)f2bf(acc[4])) | ((u32)f2bf(acc[5]) << 16);
  o.w = ((u32)f2bf(acc[6])) | ((u32)f2bf(acc[7]) << 16);
  *(uint4*)(hout + (size_t)nid * 64 + lane * 8) = o;
}

// layer-2 aggregation fused with pooling: per-node LDS rows, single barrier,
// phase-2 linear scan (no shuffles, no LDS atomics, no uniformity checks).
__global__ __launch_bounds__(256) void gpool_k(const u16* __restrict__ xw,
                                               const int* __restrict__ rowptr,
                                               const int* __restrict__ counts,
                                               const int* __restrict__ csr,
                                               const float* __restrict__ dinv,
                                               const float* __restrict__ bias,
                                               const int* __restrict__ batch,
                                               float* __restrict__ gsum,
                                               u32* __restrict__ gmax, int n) {
  __shared__ float rows[32][68];  // 32 node rows, +4 pad
  __shared__ int rowg[32];
  int t = threadIdx.x;
  int idx = blockIdx.x * 256 + t;
  int nid = idx >> 3;
  int lane = idx & 7;
  int nl = t >> 3;  // local node row
  bool active = nid < n;
  float acc[8] = {0.f, 0.f, 0.f, 0.f, 0.f, 0.f, 0.f, 0.f};
  int g = -1;
  if (active) {
    gather_node(xw, rowptr, counts, csr, dinv, bias, nid, lane, acc);
    g = batch[nid];
  }
  if (lane == 0) rowg[nl] = g;
  *(float4*)&rows[nl][lane * 8]     = make_float4(acc[0], acc[1], acc[2], acc[3]);
  *(float4*)&rows[nl][lane * 8 + 4] = make_float4(acc[4], acc[5], acc[6], acc[7]);
  // rare fallback: node's graph beyond the 4 slots phase 2 covers
  int gfirst0 = batch[(blockIdx.x * 256) >> 3];  // first node of block always < n
  if (active && g - gfirst0 >= 4) {
    #pragma unroll
    for (int i = 0; i < 8; i++) {
      atomicAdd(&gsum[g * 64 + lane * 8 + i], acc[i]);
      atomicMax(&gmax[g * 64 + lane * 8 + i], __float_as_uint(acc[i]));
    }
    if (lane == 0) rowg[nl] = -1;
  }
  __syncthreads();
  int gfirst = rowg[0];
  int gl = t >> 6;       // 0..3: handles up to 4 consecutive graphs
  int f = t & 63;
  int gg = gfirst + gl;
  float s = 0.f, m = 0.f;
  bool any = false;
  #pragma unroll 8
  for (int r = 0; r < 32; r++) {
    if (rowg[r] == gg) {
      float v = rows[r][f];
      s += v;
      m = fmaxf(m, v);
      any = true;
    }
  }
  if (any && gg >= 0 && gg < NG) {
    atomicAdd(&gsum[gg * 64 + f], s);
    atomicMax(&gmax[gg * 64 + f], __float_as_uint(m));
  }
}

// ================= finalize: xcat + head =================

__global__ __launch_bounds__(64) void fin_k(const float* __restrict__ gsum,
                                            const u32* __restrict__ gmax,
                                            const int* __restrict__ batch, int n,
                                            const float* __restrict__ Wlin,
                                            const float* __restrict__ blin,
                                            float* __restrict__ xcat,
                                            float* __restrict__ outh) {
  int g = blockIdx.x;
  int lane = threadIdx.x;
  __shared__ int se[2];
  if (lane < 2) {
    int target = g + lane;
    int lo = 0, hi = n;
    while (lo < hi) {
      int mid = (lo + hi) >> 1;
      if (batch[mid] < target) lo = mid + 1; else hi = mid;
    }
    se[lane] = lo;
  }
  __syncthreads();
  int cnt = se[1] - se[0];
  float x0 = gsum[g * 64 + lane];
  float x1 = x0 / fmaxf((float)cnt, 1.0f);
  float x2 = __uint_as_float(gmax[g * 64 + lane]);
  xcat[g * CAT + lane]       = x0;
  xcat[g * CAT + 64 + lane]  = x1;
  xcat[g * CAT + 128 + lane] = x2;
  #pragma unroll
  for (int o = 0; o < 2; o++) {
    float p = x0 * Wlin[lane * 2 + o] +
              x1 * Wlin[(64 + lane) * 2 + o] +
              x2 * Wlin[(128 + lane) * 2 + o];
    #pragma unroll
    for (int off = 32; off > 0; off >>= 1) p += __shfl_down(p, off, 64);
    if (lane == 0) outh[g * 2 + o] = p + blin[o];
  }
}

// ================= launch =================

extern "C" void kernel_launch(void* const* d_in, const int* in_sizes, int n_in,
                              void* d_out, int out_size, void* d_ws, size_t ws_size,
                              hipStream_t stream) {
  const float* x    = (const float*)d_in[0];
  const float* W1   = (const float*)d_in[1];
  const float* b1   = (const float*)d_in[2];
  const float* W2   = (const float*)d_in[3];
  const float* b2   = (const float*)d_in[4];
  const float* Wlin = (const float*)d_in[5];
  const float* blin = (const float*)d_in[6];
  const int*   ei   = (const int*)d_in[7];
  const int*   batch= (const int*)d_in[8];

  const int N = in_sizes[0] / IN_F;      // 100000
  const int E = in_sizes[7] / 2;         // 1600000
  const int* src = ei;
  const int* dst = ei + E;
  const int ndig = (N + 511) >> 9;       // 196
  const int nbE  = (E + 4095) / 4096;    // 391

  char* w = (char*)d_ws;
  auto alloc = [&](size_t bytes) {
    void* p = (void*)w;
    w += (bytes + 255) & ~(size_t)255;
    return p;
  };
  int*   rowptr = (int*)alloc((size_t)N * 4);
  int*   counts = (int*)alloc((size_t)N * 4);
  float* dinv   = (float*)alloc((size_t)N * 4);
  int*   csr    = (int*)alloc((size_t)ndig * DCAP * 4);
  int*   zbuf   = (int*)alloc((size_t)(256 + 2 * NG * 64) * 4);  // gcur | gsum | gmax
  u16*   bufA   = (u16*)alloc((size_t)N * 64 * 2);
  u16*   bufB   = (u16*)alloc((size_t)N * 64 * 2);
  u32*   stage  = (u32*)alloc((size_t)ndig * DCAP * 4);

  int*   gcur = zbuf;
  float* gsum = (float*)(zbuf + 256);
  u32*   gmax = (u32*)(zbuf + 256 + NG * 64);

  float* xcat = (float*)d_out;
  float* outh = (float*)d_out + NG * CAT;

  const int nz = 256 + 2 * NG * 64;
  zero_k  <<<(nz + 255) / 256, 256, 0, stream>>>(zbuf, nz);
  stage_k <<<nbE, 256, 0, stream>>>(src, dst, E, gcur, stage, ndig);
  csr_k   <<<ndig, 256, 0, stream>>>(stage, gcur, rowptr, counts, dinv, csr, N);

  // layer 1
  gemm_mfma_k<IN_F, false> <<<(N + 63) / 64, 256, 0, stream>>>(x, W1, bufA, N);
  gather_k <<<(N * 8 + 255) / 256, 256, 0, stream>>>(bufA, bufB, rowptr, counts, csr, dinv, b1, N);

  // layer 2 (gemm) then fused aggregation+pool
  gemm_mfma_k<C1, true> <<<(N + 63) / 64, 256, 0, stream>>>(bufB, W2, bufA, N);
  gpool_k <<<(N * 8 + 255) / 256, 256, 0, stream>>>(bufA, rowptr, counts, csr, dinv, b2,
                                                    batch, gsum, gmax, N);

  // finalize: xcat + head
  fin_k <<<NG, 64, 0, stream>>>(gsum, gmax, batch, N, Wlin, blin, xcat, outh);
}

// Round 12
// 156.141 us; speedup vs baseline: 1.1527x; 1.0194x over previous
//
#include <hip/hip_runtime.h>

#define IN_F 128
#define C1 64
#define NG 128
#define CAT 192
#define DCAP 10240   // per-digit edge capacity (mean 8163, sigma ~90)

typedef unsigned short u16;
typedef unsigned char u8;
typedef unsigned int u32;
typedef __attribute__((ext_vector_type(8))) short bf16x8;
typedef __attribute__((ext_vector_type(4))) float f32x4;

__device__ inline u16 f2bf(float f) {
  u32 u = __float_as_uint(f);
  u = (u + 0x7FFFu + ((u >> 16) & 1u)) >> 16;   // RTNE
  return (u16)u;
}
__device__ inline float bf2f(u16 h) { return __uint_as_float(((u32)h) << 16); }
__device__ inline float bflo(u32 p) { return __uint_as_float(p << 16); }
__device__ inline float bfhi(u32 p) { return __uint_as_float(p & 0xFFFF0000u); }

// ================= zero scratch (gcur only; gsum/gmax zeroed in csr_k) =================

__global__ void zero_k(int* __restrict__ g) { g[threadIdx.x] = 0; }

// ================= CSR build (bucketed; locally-sorted coalesced writes) =================

__global__ __launch_bounds__(256) void stage_k(const int* __restrict__ src,
                                               const int* __restrict__ dst, int e,
                                               int* __restrict__ gcur,
                                               u32* __restrict__ stage, int ndig) {
  __shared__ int h4[4][256];   // per-wave histograms
  __shared__ int sc[256];
  __shared__ int lcur[256];    // local placement cursors (init = local excl base)
  __shared__ int loff[256];    // bucket base + global claim - local base
  __shared__ u32 ebuf[4096];   // digit-sorted entries
  __shared__ u8  dbuf[4096];   // digit per entry
  int t = threadIdx.x;
  int wv = t >> 6;
  h4[0][t] = 0; h4[1][t] = 0; h4[2][t] = 0; h4[3][t] = 0;
  __syncthreads();
  int base = blockIdx.x * 4096;
  int tot = min(4096, e - base);
  int mys[16], myd[16];
  #pragma unroll
  for (int i = 0; i < 16; i++) {
    int j = base + t + i * 256;
    if (j < e) {
      mys[i] = src[j];
      myd[i] = dst[j];
      atomicAdd(&h4[wv][myd[i] >> 9], 1);
    } else {
      myd[i] = -1;
    }
  }
  __syncthreads();
  int cnt = h4[0][t] + h4[1][t] + h4[2][t] + h4[3][t];
  // exclusive scan of cnt over 256 digits
  sc[t] = cnt;
  __syncthreads();
  #pragma unroll
  for (int off = 1; off < 256; off <<= 1) {
    int x = sc[t] + ((t >= off) ? sc[t - off] : 0);
    __syncthreads();
    sc[t] = x;
    __syncthreads();
  }
  int excl = sc[t] - cnt;
  int gbase = 0;
  if (t < ndig && cnt > 0) gbase = atomicAdd(&gcur[t], cnt);
  lcur[t] = excl;
  loff[t] = t * DCAP + gbase - excl;   // FIX: include per-digit bucket base t*DCAP
  __syncthreads();
  // place entries digit-sorted in LDS
  #pragma unroll
  for (int i = 0; i < 16; i++) {
    if (myd[i] >= 0) {
      int d = myd[i] >> 9;
      int r = atomicAdd(&lcur[d], 1);
      ebuf[r] = (u32)mys[i] | ((u32)(myd[i] & 511) << 17);
      dbuf[r] = (u8)d;
    }
  }
  __syncthreads();
  // coalesced global write: consecutive j -> consecutive stage addresses per digit run
  for (int j = t; j < tot; j += 256) {
    int d = dbuf[j];
    stage[loff[d] + j] = ebuf[j];
  }
}

__global__ __launch_bounds__(256) void csr_k(const u32* __restrict__ stage,
                                             const int* __restrict__ gcur,
                                             int* __restrict__ rowptr,
                                             int* __restrict__ counts,
                                             float* __restrict__ dinv,
                                             int* __restrict__ csr,
                                             int* __restrict__ zeroA, int nz, int n) {
  __shared__ int hc[512];
  __shared__ int hb[512];
  __shared__ int cu[512];
  __shared__ int sc[256];
  __shared__ u32 lbuf[DCAP];   // digit's csr image, written coalesced at the end
  int dg = blockIdx.x;
  int t = threadIdx.x;
  {  // absorb gsum/gmax zeroing (csr_k precedes gpool_k on the stream)
    int zi = dg * 256 + t;
    if (zi < nz) zeroA[zi] = 0;
  }
  int n0 = dg * 512;
  int nloc = min(n - n0, 512);
  int e0 = dg * DCAP;
  int cntE = gcur[dg];
  hc[t] = 0; hc[t + 256] = 0;
  __syncthreads();
  for (int j = t; j < cntE; j += 256) atomicAdd(&hc[stage[e0 + j] >> 17], 1);
  __syncthreads();
  int a0 = hc[2 * t], a1 = hc[2 * t + 1];
  int s = a0 + a1;
  sc[t] = s;
  __syncthreads();
  #pragma unroll
  for (int off = 1; off < 256; off <<= 1) {
    int x = sc[t] + ((t >= off) ? sc[t - off] : 0);
    __syncthreads();
    sc[t] = x;
    __syncthreads();
  }
  int excl = sc[t] - s;
  hb[2 * t] = excl;
  hb[2 * t + 1] = excl + a0;
  cu[2 * t] = 0; cu[2 * t + 1] = 0;
  __syncthreads();
  for (int i = t; i < nloc; i += 256) {
    int node = n0 + i;
    rowptr[node] = e0 + hb[i];
    counts[node] = hc[i];
    dinv[node] = rsqrtf((float)hc[i] + 1.0f);  // +1 self loop
  }
  __syncthreads();
  for (int j = t; j < cntE; j += 256) {
    u32 p = stage[e0 + j];
    int li = p >> 17;
    int r = atomicAdd(&cu[li], 1);
    lbuf[hb[li] + r] = p & 0x1FFFFu;
  }
  __syncthreads();
  for (int j = t; j < cntE; j += 256) csr[e0 + j] = (int)lbuf[j];
}

// ================= MFMA GEMM  Y[N,64](bf16) = X[N,K] @ W[K,64] =================

template <int K, bool IN_BF16>
__global__ __launch_bounds__(256) void gemm_mfma_k(const void* __restrict__ Xv,
                                                   const float* __restrict__ W,
                                                   u16* __restrict__ Y, int n) {
  constexpr int KK = K / 32;
  constexpr int XSN = 2048 * KK;
  constexpr int TOT = 4096 * KK;
  constexpr int SMEMN = (TOT > 9216) ? TOT : 9216;
  __shared__ u16 smem[SMEMN];
  u16* Xs = smem;
  u16* Ws = smem + XSN;
  int t = threadIdx.x;
  int row0 = blockIdx.x * 64;

  for (int idx = t; idx < K * 16; idx += 256) {
    int k = idx >> 4, c4 = (idx & 15) * 4;
    float4 wv = *(const float4*)(W + (size_t)k * 64 + c4);
    int kk = k >> 5, k8 = (k & 31) >> 3, kr = k & 7;
    float wa[4] = {wv.x, wv.y, wv.z, wv.w};
    #pragma unroll
    for (int j = 0; j < 4; j++) {
      int c = c4 + j;
      u32 byte = (u32)(((kk * 64 + c) * 32 + k8 * 8 + kr) * 2);
      byte ^= (u32)((c & 7) << 4);
      *(u16*)((char*)Ws + byte) = f2bf(wa[j]);
    }
  }

  for (int idx = t; idx < 8 * K; idx += 256) {
    int r = idx / (K / 8);
    int c8 = idx % (K / 8);
    int gr = row0 + r;
    u16 vals[8];
    if (gr < n) {
      if (IN_BF16) {
        *(uint4*)vals = *(const uint4*)((const u16*)Xv + (size_t)gr * K + c8 * 8);
      } else {
        const float4 x0 = *(const float4*)((const float*)Xv + (size_t)gr * K + c8 * 8);
        const float4 x1 = *(const float4*)((const float*)Xv + (size_t)gr * K + c8 * 8 + 4);
        vals[0] = f2bf(x0.x); vals[1] = f2bf(x0.y); vals[2] = f2bf(x0.z); vals[3] = f2bf(x0.w);
        vals[4] = f2bf(x1.x); vals[5] = f2bf(x1.y); vals[6] = f2bf(x1.z); vals[7] = f2bf(x1.w);
      }
    } else {
      #pragma unroll
      for (int j = 0; j < 8; j++) vals[j] = 0;
    }
    int wrow = r >> 4, row = r & 15, kk = c8 >> 2, k8 = c8 & 3;
    u32 byte = (u32)((((wrow * KK + kk) * 16 + row) * 32 + k8 * 8) * 2);
    byte ^= (u32)((row & 7) << 4);
    *(uint4*)((char*)Xs + byte) = *(uint4*)vals;
  }
  __syncthreads();

  int w = t >> 6, l = t & 63;
  int lrow = l & 15, lk = l >> 4;
  bf16x8 bfrag[KK][4];
  #pragma unroll
  for (int kk = 0; kk < KK; kk++) {
    #pragma unroll
    for (int cb = 0; cb < 4; cb++) {
      int col = cb * 16 + lrow;
      u32 byte = (u32)(((kk * 64 + col) * 32 + lk * 8) * 2);
      byte ^= (u32)((col & 7) << 4);
      bfrag[kk][cb] = *(bf16x8*)((char*)Ws + byte);
    }
  }
  f32x4 acc[4] = {};
  #pragma unroll
  for (int kk = 0; kk < KK; kk++) {
    u32 abyte = (u32)((((w * KK + kk) * 16 + lrow) * 32 + lk * 8) * 2);
    abyte ^= (u32)((lrow & 7) << 4);
    bf16x8 a = *(bf16x8*)((char*)Xs + abyte);
    #pragma unroll
    for (int cb = 0; cb < 4; cb++) {
      acc[cb] = __builtin_amdgcn_mfma_f32_16x16x32_bf16(a, bfrag[kk][cb], acc[cb], 0, 0, 0);
    }
  }
  __syncthreads();

  #pragma unroll
  for (int cb = 0; cb < 4; cb++) {
    #pragma unroll
    for (int reg = 0; reg < 4; reg++) {
      int r = w * 16 + lk * 4 + reg;
      int c = cb * 16 + lrow;
      smem[r * 72 + c] = f2bf(acc[cb][reg]);
    }
  }
  __syncthreads();
  #pragma unroll
  for (int p = 0; p < 2; p++) {
    int idx = t + p * 256;
    int rr = idx >> 3, ch = idx & 7;
    int gr = row0 + rr;
    if (gr < n) {
      uint4 v = *(uint4*)&smem[rr * 72 + ch * 8];
      *(uint4*)(Y + (size_t)gr * 64 + ch * 8) = v;
    }
  }
}

// ================= gather core =================

__device__ __forceinline__ void gather_node(const u16* __restrict__ xw,
                                            const int* __restrict__ rowptr,
                                            const int* __restrict__ counts,
                                            const int* __restrict__ csr,
                                            const float* __restrict__ dinv,
                                            const float* __restrict__ bias,
                                            int nid, int lane, float acc[8]) {
  float di = dinv[nid];
  float sc = di * di;
  {
    uint4 a = *(const uint4*)(xw + (size_t)nid * 64 + lane * 8);
    acc[0] = bflo(a.x) * sc; acc[1] = bfhi(a.x) * sc;
    acc[2] = bflo(a.y) * sc; acc[3] = bfhi(a.y) * sc;
    acc[4] = bflo(a.z) * sc; acc[5] = bfhi(a.z) * sc;
    acc[6] = bflo(a.w) * sc; acc[7] = bfhi(a.w) * sc;
  }
  int st = rowptr[nid];
  int cn = counts[nid];
  int myidx = 0;
  float dv = 0.f;
  if (lane < cn) {
    myidx = csr[st + lane];
    dv = dinv[myidx];
  }
  for (int c = 0; c < cn; c += 8) {
    int rem = cn - c;
    uint4 vv[8];
    #pragma unroll
    for (int i = 0; i < 8; i++) {
      int s = __shfl(myidx, i, 8);
      if (i < rem) {
        vv[i] = *(const uint4*)(xw + (size_t)s * 64 + lane * 8);
      } else {
        vv[i] = make_uint4(0, 0, 0, 0);
      }
    }
    float ww[8];
    float myw = dv * di;
    #pragma unroll
    for (int i = 0; i < 8; i++) ww[i] = (i < rem) ? __shfl(myw, i, 8) : 0.f;
    int nxt = 0;
    float ndv = 0.f;
    if (c + 8 < cn && lane < rem - 8) {
      nxt = csr[st + c + 8 + lane];
      ndv = dinv[nxt];
    }
    #pragma unroll
    for (int i = 0; i < 8; i++) {
      float wgt = ww[i];
      acc[0] += bflo(vv[i].x) * wgt; acc[1] += bfhi(vv[i].x) * wgt;
      acc[2] += bflo(vv[i].y) * wgt; acc[3] += bfhi(vv[i].y) * wgt;
      acc[4] += bflo(vv[i].z) * wgt; acc[5] += bfhi(vv[i].z) * wgt;
      acc[6] += bflo(vv[i].w) * wgt; acc[7] += bfhi(vv[i].w) * wgt;
    }
    myidx = nxt;
    dv = ndv;
  }
  const float4 b0 = *(const float4*)(bias + lane * 8);
  const float4 b1 = *(const float4*)(bias + lane * 8 + 4);
  acc[0] = fmaxf(acc[0] + b0.x, 0.f);
  acc[1] = fmaxf(acc[1] + b0.y, 0.f);
  acc[2] = fmaxf(acc[2] + b0.z, 0.f);
  acc[3] = fmaxf(acc[3] + b0.w, 0.f);
  acc[4] = fmaxf(acc[4] + b1.x, 0.f);
  acc[5] = fmaxf(acc[5] + b1.y, 0.f);
  acc[6] = fmaxf(acc[6] + b1.z, 0.f);
  acc[7] = fmaxf(acc[7] + b1.w, 0.f);
}

// layer-1 aggregation: store h1 bf16 (no barrier -> no straggler)
__global__ __launch_bounds__(256) void gather_k(const u16* __restrict__ xw,
                                                u16* __restrict__ hout,
                                                const int* __restrict__ rowptr,
                                                const int* __restrict__ counts,
                                                const int* __restrict__ csr,
                                                const float* __restrict__ dinv,
                                                const float* __restrict__ bias, int n) {
  int idx = blockIdx.x * 256 + threadIdx.x;
  int nid = idx >> 3;
  int lane = idx & 7;
  if (nid >= n) return;
  float acc[8];
  gather_node(xw, rowptr, counts, csr, dinv, bias, nid, lane, acc);
  uint4 o;
  o.x = ((u32)f2bf(acc[0])) | ((u32)f2bf(acc[1]) << 16);
  o.y = ((u32)f2bf(acc[2])) | ((u32)f2bf(acc[3]) << 16);
  o.z = ((u32)f2bf(acc[4])) | ((u32)f2bf(acc[5]) << 16);
  o.w = ((u32)f2bf(acc[6])) | ((u32)f2bf(acc[7]) << 16);
  *(uint4*)(hout + (size_t)nid * 64 + lane * 8) = o;
}

// layer-2 aggregation fused with pooling: 128 nodes/block, 4 sequential nodes
// per 8-lane group (averages the degree tail before the single barrier).
__global__ __launch_bounds__(256) void gpool_k(const u16* __restrict__ xw,
                                               const int* __restrict__ rowptr,
                                               const int* __restrict__ counts,
                                               const int* __restrict__ csr,
                                               const float* __restrict__ dinv,
                                               const float* __restrict__ bias,
                                               const int* __restrict__ batch,
                                               float* __restrict__ gsum,
                                               u32* __restrict__ gmax, int n) {
  __shared__ float rows[128][68];
  __shared__ int rowg[128];
  int t = threadIdx.x;
  int grp = t >> 3;
  int lane = t & 7;
  int nbase = blockIdx.x * 128;
  int gfirst = batch[nbase < n ? nbase : (n - 1)];
  for (int p = 0; p < 4; p++) {
    int nl = p * 32 + grp;
    int nid = nbase + nl;
    float acc[8] = {0.f, 0.f, 0.f, 0.f, 0.f, 0.f, 0.f, 0.f};
    int g = -1;
    if (nid < n) {
      gather_node(xw, rowptr, counts, csr, dinv, bias, nid, lane, acc);
      g = batch[nid];
      if (g - gfirst >= 4) {  // rare: beyond phase-2's 4-graph window
        #pragma unroll
        for (int i = 0; i < 8; i++) {
          atomicAdd(&gsum[g * 64 + lane * 8 + i], acc[i]);
          atomicMax(&gmax[g * 64 + lane * 8 + i], __float_as_uint(acc[i]));
        }
        g = -1;
      }
    }
    if (lane == 0) rowg[nl] = g;
    *(float4*)&rows[nl][lane * 8]     = make_float4(acc[0], acc[1], acc[2], acc[3]);
    *(float4*)&rows[nl][lane * 8 + 4] = make_float4(acc[4], acc[5], acc[6], acc[7]);
  }
  __syncthreads();
  int gl = t >> 6;       // wave-uniform: 4 consecutive graphs covered
  int f = t & 63;
  int gg = gfirst + gl;
  float s = 0.f, m = 0.f;
  bool any = false;
  #pragma unroll 8
  for (int r = 0; r < 128; r++) {
    if (rowg[r] == gg) {
      float v = rows[r][f];
      s += v;
      m = fmaxf(m, v);
      any = true;
    }
  }
  if (any && gg < NG) {
    atomicAdd(&gsum[gg * 64 + f], s);
    atomicMax(&gmax[gg * 64 + f], __float_as_uint(m));
  }
}

// ================= finalize: xcat + head =================

__global__ __launch_bounds__(64) void fin_k(const float* __restrict__ gsum,
                                            const u32* __restrict__ gmax,
                                            const int* __restrict__ batch, int n,
                                            const float* __restrict__ Wlin,
                                            const float* __restrict__ blin,
                                            float* __restrict__ xcat,
                                            float* __restrict__ outh) {
  int g = blockIdx.x;
  int lane = threadIdx.x;
  __shared__ int se[2];
  if (lane < 2) {
    int target = g + lane;
    int lo = 0, hi = n;
    while (lo < hi) {
      int mid = (lo + hi) >> 1;
      if (batch[mid] < target) lo = mid + 1; else hi = mid;
    }
    se[lane] = lo;
  }
  __syncthreads();
  int cnt = se[1] - se[0];
  float x0 = gsum[g * 64 + lane];
  float x1 = x0 / fmaxf((float)cnt, 1.0f);
  float x2 = __uint_as_float(gmax[g * 64 + lane]);
  xcat[g * CAT + lane]       = x0;
  xcat[g * CAT + 64 + lane]  = x1;
  xcat[g * CAT + 128 + lane] = x2;
  #pragma unroll
  for (int o = 0; o < 2; o++) {
    float p = x0 * Wlin[lane * 2 + o] +
              x1 * Wlin[(64 + lane) * 2 + o] +
              x2 * Wlin[(128 + lane) * 2 + o];
    #pragma unroll
    for (int off = 32; off > 0; off >>= 1) p += __shfl_down(p, off, 64);
    if (lane == 0) outh[g * 2 + o] = p + blin[o];
  }
}

// ================= launch =================

extern "C" void kernel_launch(void* const* d_in, const int* in_sizes, int n_in,
                              void* d_out, int out_size, void* d_ws, size_t ws_size,
                              hipStream_t stream) {
  const float* x    = (const float*)d_in[0];
  const float* W1   = (const float*)d_in[1];
  const float* b1   = (const float*)d_in[2];
  const float* W2   = (const float*)d_in[3];
  const float* b2   = (const float*)d_in[4];
  const float* Wlin = (const float*)d_in[5];
  const float* blin = (const float*)d_in[6];
  const int*   ei   = (const int*)d_in[7];
  const int*   batch= (const int*)d_in[8];

  const int N = in_sizes[0] / IN_F;      // 100000
  const int E = in_sizes[7] / 2;         // 1600000
  const int* src = ei;
  const int* dst = ei + E;
  const int ndig = (N + 511) >> 9;       // 196
  const int nbE  = (E + 4095) / 4096;    // 391

  char* w = (char*)d_ws;
  auto alloc = [&](size_t bytes) {
    void* p = (void*)w;
    w += (bytes + 255) & ~(size_t)255;
    return p;
  };
  int*   rowptr = (int*)alloc((size_t)N * 4);
  int*   counts = (int*)alloc((size_t)N * 4);
  float* dinv   = (float*)alloc((size_t)N * 4);
  int*   csr    = (int*)alloc((size_t)ndig * DCAP * 4);
  int*   zbuf   = (int*)alloc((size_t)(256 + 2 * NG * 64) * 4);  // gcur | gsum | gmax
  u16*   bufA   = (u16*)alloc((size_t)N * 64 * 2);
  u16*   bufB   = (u16*)alloc((size_t)N * 64 * 2);
  u32*   stage  = (u32*)alloc((size_t)ndig * DCAP * 4);

  int*   gcur = zbuf;
  float* gsum = (float*)(zbuf + 256);
  u32*   gmax = (u32*)(zbuf + 256 + NG * 64);

  float* xcat = (float*)d_out;
  float* outh = (float*)d_out + NG * CAT;

  zero_k  <<<1, 256, 0, stream>>>(gcur);
  stage_k <<<nbE, 256, 0, stream>>>(src, dst, E, gcur, stage, ndig);
  csr_k   <<<ndig, 256, 0, stream>>>(stage, gcur, rowptr, counts, dinv, csr,
                                     zbuf + 256, 2 * NG * 64, N);

  // layer 1
  gemm_mfma_k<IN_F, false> <<<(N + 63) / 64, 256, 0, stream>>>(x, W1, bufA, N);
  gather_k <<<(N * 8 + 255) / 256, 256, 0, stream>>>(bufA, bufB, rowptr, counts, csr, dinv, b1, N);

  // layer 2 (gemm) then fused aggregation+pool
  gemm_mfma_k<C1, true> <<<(N + 63) / 64, 256, 0, stream>>>(bufB, W2, bufA, N);
  gpool_k <<<(N + 127) / 128, 256, 0, stream>>>(bufA, rowptr, counts, csr, dinv, b2,
                                                batch, gsum, gmax, N);

  // finalize: xcat + head
  fin_k <<<NG, 64, 0, stream>>>(gsum, gmax, batch, N, Wlin, blin, xcat, outh);
}